// Round 7
// baseline (4681.721 us; speedup 1.0000x reference)
//
#include <hip/hip_runtime.h>
#include <cstdint>
#include <cstddef>

// R7: persistent slice-exchange RNN — R4 protocol + poll backoff + LDS fix.
// 256 WGs = 4 slice-WGs per batch x 64 batches, 512 threads each.
// Exchange: self-validating tagged ring at the MALL (agent-scope relaxed
// atomics; proven in R4 across graph replays). Each h element is one 8B word
// (tag=t << 32)|fp32; readers poll the data word itself until tag==t-1.
// NEW vs R4:
//  (1) s_sleep(8) backoff in the poll loop — R4 had no backoff, and ~12k
//      lanes re-polling every ~40cy (~20TB/s demand) congested the MALL,
//      delaying the writer's own store visibility (~8.5k cy edge).
//  (2) out-projection reads LDS at k=16j+oc -> 16 distinct banks, broadcast
//      across o-groups (kills the 4-way conflict, 3.36e7 -> ~0).
// One barrier per step. No placement assumptions anywhere.

#define BB 64
#define TT 1024
#define II 64
#define HH 512
#define OO 64

__device__ __forceinline__ float tanh_fast(float v) {
  float e = exp2f(fabsf(v) * 2.8853900817779268f);
  float r = 1.0f - 2.0f * __builtin_amdgcn_rcpf(e + 1.0f);
  return copysignf(r, v);
}

__global__ __launch_bounds__(512, 1) void rnn_persist(
    const float* __restrict__ x, const float* __restrict__ h0,
    const float* __restrict__ Wih, const float* __restrict__ Whh,
    const float* __restrict__ bih, const float* __restrict__ bhh,
    const float* __restrict__ Wout, const float* __restrict__ bout,
    float* __restrict__ out, unsigned long long* __restrict__ ring) {
  const int tid = threadIdx.x;
  const int b   = blockIdx.x & 63;   // batch element
  const int q   = blockIdx.x >> 6;   // slice quarter
  const int n   = tid >> 2;          // local output row 0..127
  const int q4  = tid & 3;           // k-quarter (128 k's each)
  const int row = q * 128 + n;       // global row in H

  __shared__ float h2[2][4][132];
  __shared__ float x2[2][II];

  // ---- register-resident weights ----
  float wh[128];
#pragma unroll
  for (int j = 0; j < 32; ++j) {
    const float4 v = *(const float4*)(Whh + (size_t)row * HH + q4 * 128 + j * 4);
    wh[4*j+0] = v.x; wh[4*j+1] = v.y; wh[4*j+2] = v.z; wh[4*j+3] = v.w;
  }
  float wi[16];
#pragma unroll
  for (int j = 0; j < 4; ++j) {
    const float4 v = *(const float4*)(Wih + (size_t)row * II + q4 * 16 + j * 4);
    wi[4*j+0] = v.x; wi[4*j+1] = v.y; wi[4*j+2] = v.z; wi[4*j+3] = v.w;
  }
  const float bias_n = bih[row] + bhh[row];

  // out-proj weights: waves 0-3 only. 16 outputs/WG, 16 lanes per output.
  // Lane oc covers k = 16j + oc -> LDS reads hit 16 distinct banks
  // (broadcast across the 4 o-groups): conflict-free.
  const int l     = tid & 63;
  const int oc    = l & 15;
  const int o_loc = (tid >> 6) * 4 + (l >> 4);
  float wo[32];
  float bo = 0.0f;
  if (tid < 256) {
    const int o = q * 16 + o_loc;
#pragma unroll
    for (int j = 0; j < 32; ++j) wo[j] = Wout[(size_t)o * HH + oc + 16 * j];
    bo = bout[o];
  }

  const float* xb           = x + (size_t)b * TT * II;
  unsigned long long* ringb = ring + (size_t)b * 2 * HH;
  float* outb               = out + (size_t)b * TT * OO;

  for (int t = 1; t <= TT + 1; ++t) {
    const int hs = (t - 1) & 1;  // LDS/ring slot holding h_{t-1}

    // stage x[b, t-1] -> x2[t&1] (overlaps sibling polls)
    if (t <= TT && tid >= 256 && tid < 272) {
      const int j = tid - 256;
      const float4 v = *(const float4*)(xb + (size_t)(t - 1) * II + j * 4);
      *(float4*)&x2[t & 1][j * 4] = v;
    }

    // stage h_{t-1}: wave w handles quarter w, skips own quarter (deposited
    // into h2[hs][q] by the writer last step).
    if (tid < 256) {
      const int w  = tid >> 6;
      const int e0 = tid * 2;
      if (t == 1) {
        const float2 hv = *(const float2*)(h0 + (size_t)b * HH + e0);
        h2[0][w][e0 & 127]       = hv.x;
        h2[0][w][(e0 & 127) + 1] = hv.y;
      } else if (w != q) {
        const unsigned tgt = (unsigned)(t - 1);
        const unsigned long long* p0 = ringb + (size_t)hs * HH + e0;
        // first try (no sleep): data usually arrived during our out-proj
        unsigned long long v0 = __hip_atomic_load(p0,     __ATOMIC_RELAXED, __HIP_MEMORY_SCOPE_AGENT);
        unsigned long long v1 = __hip_atomic_load(p0 + 1, __ATOMIC_RELAXED, __HIP_MEMORY_SCOPE_AGENT);
        bool d0 = ((unsigned)(v0 >> 32) == tgt);
        bool d1 = ((unsigned)(v1 >> 32) == tgt);
        while (!(d0 && d1)) {
          __builtin_amdgcn_s_sleep(8);  // ~512cy backoff: keep MALL unclogged
          if (!d0) {
            unsigned long long tv = __hip_atomic_load(p0,     __ATOMIC_RELAXED, __HIP_MEMORY_SCOPE_AGENT);
            if ((unsigned)(tv >> 32) == tgt) { v0 = tv; d0 = true; }
          }
          if (!d1) {
            unsigned long long tv = __hip_atomic_load(p0 + 1, __ATOMIC_RELAXED, __HIP_MEMORY_SCOPE_AGENT);
            if ((unsigned)(tv >> 32) == tgt) { v1 = tv; d1 = true; }
          }
        }
        h2[hs][w][e0 & 127]       = __uint_as_float((unsigned)v0);
        h2[hs][w][(e0 & 127) + 1] = __uint_as_float((unsigned)v1);
      }
    }
    __syncthreads();

    if (t <= TT) {
      // ---- recurrent matvec: this thread's 128-k chunk of row `row` ----
      const float* hp = &h2[hs][q4][0];
      float a0 = 0.f, a1 = 0.f, a2 = 0.f, a3 = 0.f;
#pragma unroll
      for (int j = 0; j < 128; j += 4) {
        a0 = fmaf(wh[j+0], hp[j+0], a0);
        a1 = fmaf(wh[j+1], hp[j+1], a1);
        a2 = fmaf(wh[j+2], hp[j+2], a2);
        a3 = fmaf(wh[j+3], hp[j+3], a3);
      }
      // ---- input projection ----
      float ax = 0.f;
      const float* xp = &x2[t & 1][q4 * 16];
#pragma unroll
      for (int j = 0; j < 16; ++j) ax = fmaf(wi[j], xp[j], ax);

      float a = (a0 + a1) + (a2 + a3) + ax;
      a += __shfl_xor(a, 1);
      a += __shfl_xor(a, 2);
      if (q4 == 0) {
        const float hnew = tanh_fast(a + bias_n);
        h2[t & 1][q][n] = hnew;  // own quarter straight into next LDS slot
        // publish (tag | value) — self-validating, agent scope at the MALL
        __hip_atomic_store(ringb + (size_t)(t & 1) * HH + row,
                           ((unsigned long long)(unsigned)t << 32) |
                               __float_as_uint(hnew),
                           __ATOMIC_RELAXED, __HIP_MEMORY_SCOPE_AGENT);
      }
    }

    // ---- out-projection for tau = t-2 (absorbed by next step's poll wait) ----
    if (t >= 2 && tid < 256) {
      float s0 = 0.f, s1 = 0.f;
#pragma unroll
      for (int j = 0; j < 32; j += 2) {
        s0 = fmaf(wo[j+0], h2[hs][(j+0) >> 3][oc + 16 * ((j+0) & 7)], s0);
        s1 = fmaf(wo[j+1], h2[hs][(j+1) >> 3][oc + 16 * ((j+1) & 7)], s1);
      }
      float s = s0 + s1;
      s += __shfl_xor(s, 1);
      s += __shfl_xor(s, 2);
      s += __shfl_xor(s, 4);
      s += __shfl_xor(s, 8);
      if (oc == 0) {
        outb[(size_t)(t - 2) * OO + q * 16 + o_loc] = tanh_fast(s + bo);
      }
    }

    // ---- final hidden state h_T -> d_out tail ----
    if (t == TT + 1 && q == 0 && tid < 256) {
      const int e0 = tid * 2;
      float* hout = out + (size_t)BB * TT * OO + (size_t)b * HH + e0;
      hout[0] = h2[hs][e0 >> 7][e0 & 127];
      hout[1] = h2[hs][e0 >> 7][(e0 & 127) + 1];
    }
  }
}

extern "C" void kernel_launch(void* const* d_in, const int* in_sizes, int n_in,
                              void* d_out, int out_size, void* d_ws, size_t ws_size,
                              hipStream_t stream) {
  (void)in_sizes; (void)n_in; (void)out_size; (void)ws_size;
  const float* x    = (const float*)d_in[0];
  const float* h0   = (const float*)d_in[1];
  const float* Wih  = (const float*)d_in[2];
  const float* Whh  = (const float*)d_in[3];
  const float* bih  = (const float*)d_in[4];
  const float* bhh  = (const float*)d_in[5];
  const float* Wout = (const float*)d_in[6];
  const float* bout = (const float*)d_in[7];
  float* out = (float*)d_out;

  unsigned long long* ring = (unsigned long long*)d_ws;  // 64 x 2 x 512 x 8B

  // ring tags must be zero at the start of every (replayed) launch
  hipMemsetAsync(d_ws, 0, (size_t)BB * 2 * HH * 8, stream);

  rnn_persist<<<dim3(256), dim3(512), 0, stream>>>(
      x, h0, Wih, Whh, bih, bhh, Wout, bout, out, ring);
}

// Round 8
// 4303.172 us; speedup vs baseline: 1.0880x; 1.0880x over previous
//
#include <hip/hip_runtime.h>
#include <cstdint>
#include <cstddef>

// R8: persistent slice-exchange RNN — R4 protocol + x-prefetch + bf16-pair ring.
// 256 WGs = 4 slice-WGs per batch x 64 batches, 512 threads each.
// Exchange: self-validating tagged ring at the MALL (agent-scope relaxed
// atomics, tag-in-data, single round trip; replay-safe as proven in R4/R7).
// NEW vs R7:
//  (1) no s_sleep (R7 showed backoff costs ~1.5k cy/step)
//  (2) x[t] prefetched into REGISTERS at step t, written to LDS after the
//      barrier, consumed at t+1 -> the ~900cy HBM load leaves the critical path
//  (3) ring words pack TWO rows as bf16: (tag32 | bf16 hi-row | bf16 lo-row).
//      Polls: 384->192 words/WG-step (1 per thread, tid<192); publishes:
//      128->64. Own quarter stays fp32 in LDS; bf16 injection error ~3e-4,
//      recurrence gain ~0.58 -> steady-state ~1e-3 << 0.0154 threshold.

#define BB 64
#define TT 1024
#define II 64
#define HH 512
#define OO 64

__device__ __forceinline__ float tanh_fast(float v) {
  float e = exp2f(fabsf(v) * 2.8853900817779268f);
  float r = 1.0f - 2.0f * __builtin_amdgcn_rcpf(e + 1.0f);
  return copysignf(r, v);
}

__device__ __forceinline__ unsigned f2bf(float f) {  // RTNE
  unsigned u = __float_as_uint(f);
  return (u + 0x7fffu + ((u >> 16) & 1u)) >> 16;
}
__device__ __forceinline__ float bf2f(unsigned b) {
  return __uint_as_float(b << 16);
}

__global__ __launch_bounds__(512, 1) void rnn_persist(
    const float* __restrict__ x, const float* __restrict__ h0,
    const float* __restrict__ Wih, const float* __restrict__ Whh,
    const float* __restrict__ bih, const float* __restrict__ bhh,
    const float* __restrict__ Wout, const float* __restrict__ bout,
    float* __restrict__ out, unsigned long long* __restrict__ ring) {
  const int tid = threadIdx.x;
  const int b   = blockIdx.x & 63;   // batch element
  const int q   = blockIdx.x >> 6;   // slice quarter
  const int n   = tid >> 2;          // local output row 0..127
  const int q4  = tid & 3;           // k-quarter (128 k's each)
  const int row = q * 128 + n;       // global row in H

  __shared__ float h2[2][4][132];
  __shared__ float x2[2][II];

  // ---- register-resident weights ----
  float wh[128];
#pragma unroll
  for (int j = 0; j < 32; ++j) {
    const float4 v = *(const float4*)(Whh + (size_t)row * HH + q4 * 128 + j * 4);
    wh[4*j+0] = v.x; wh[4*j+1] = v.y; wh[4*j+2] = v.z; wh[4*j+3] = v.w;
  }
  float wi[16];
#pragma unroll
  for (int j = 0; j < 4; ++j) {
    const float4 v = *(const float4*)(Wih + (size_t)row * II + q4 * 16 + j * 4);
    wi[4*j+0] = v.x; wi[4*j+1] = v.y; wi[4*j+2] = v.z; wi[4*j+3] = v.w;
  }
  const float bias_n = bih[row] + bhh[row];

  // out-proj weights: waves 0-3 only; lane oc covers k=16j+oc (conflict-free)
  const int l     = tid & 63;
  const int oc    = l & 15;
  const int o_loc = (tid >> 6) * 4 + (l >> 4);
  float wo[32];
  float bo = 0.0f;
  if (tid < 256) {
    const int o = q * 16 + o_loc;
#pragma unroll
    for (int j = 0; j < 32; ++j) wo[j] = Wout[(size_t)o * HH + oc + 16 * j];
    bo = bout[o];
  }

  const float* xb           = x + (size_t)b * TT * II;
  unsigned long long* ringb = ring + (size_t)b * 2 * 256;  // 2 slots x 256 words
  float* outb               = out + (size_t)b * TT * OO;

  const bool xloader = (tid >= 256 && tid < 272);
  // pre-stage x[0] into slot 1 (used by compute at t=1)
  if (xloader) {
    const int j = tid - 256;
    *(float4*)&x2[1][j * 4] = *(const float4*)(xb + j * 4);
  }

  for (int t = 1; t <= TT + 1; ++t) {
    const int hs = (t - 1) & 1;  // LDS/ring slot holding h_{t-1}

    // (2) prefetch x[t] into REGISTERS (consumed at step t+1)
    float4 xv;
    if (t < TT && xloader) {
      xv = *(const float4*)(xb + (size_t)t * II + (tid - 256) * 4);
    }

    // stage h_{t-1}: tid<192 each poll ONE packed word of a sibling quarter
    if (t == 1) {
      if (tid < 256) {
        const int e0 = tid * 2;
        const float2 hv = *(const float2*)(h0 + (size_t)b * HH + e0);
        h2[0][tid >> 6][e0 & 127]       = hv.x;
        h2[0][tid >> 6][(e0 & 127) + 1] = hv.y;
      }
    } else if (tid < 192) {
      const int wq = tid >> 6;
      const int w  = wq + (wq >= q);   // skip own quarter
      const int m  = tid & 63;         // rows 2m, 2m+1 of quarter w
      const unsigned tgt = (unsigned)(t - 1);
      const unsigned long long* p = ringb + (size_t)hs * 256 + w * 64 + m;
      unsigned long long v =
          __hip_atomic_load(p, __ATOMIC_RELAXED, __HIP_MEMORY_SCOPE_AGENT);
      while ((unsigned)(v >> 32) != tgt) {
        v = __hip_atomic_load(p, __ATOMIC_RELAXED, __HIP_MEMORY_SCOPE_AGENT);
      }
      const unsigned lo = (unsigned)v & 0xffffu;
      const unsigned hi = ((unsigned)v >> 16) & 0xffffu;
      *(float2*)&h2[hs][w][2 * m] = make_float2(bf2f(lo), bf2f(hi));
    }
    __syncthreads();

    // write prefetched x to LDS slot (t+1)&1 — hidden under compute
    if (t < TT && xloader) {
      *(float4*)&x2[(t + 1) & 1][(tid - 256) * 4] = xv;
    }

    if (t <= TT) {
      // ---- recurrent matvec: this thread's 128-k chunk of row `row` ----
      const float* hp = &h2[hs][q4][0];
      float a0 = 0.f, a1 = 0.f, a2 = 0.f, a3 = 0.f;
#pragma unroll
      for (int j = 0; j < 128; j += 4) {
        a0 = fmaf(wh[j+0], hp[j+0], a0);
        a1 = fmaf(wh[j+1], hp[j+1], a1);
        a2 = fmaf(wh[j+2], hp[j+2], a2);
        a3 = fmaf(wh[j+3], hp[j+3], a3);
      }
      // ---- input projection ----
      float ax = 0.f;
      const float* xp = &x2[t & 1][q4 * 16];
#pragma unroll
      for (int j = 0; j < 16; ++j) ax = fmaf(wi[j], xp[j], ax);

      float a = (a0 + a1) + (a2 + a3) + ax;
      a += __shfl_xor(a, 1);
      a += __shfl_xor(a, 2);
      // all 4 q4-lanes now hold the full row sum
      const float hnew = tanh_fast(a + bias_n);
      const float pv   = __shfl_xor(hnew, 4);  // partner row n^1's value
      if (q4 == 0) {
        h2[t & 1][q][n] = hnew;  // own quarter, fp32, straight into next slot
        if ((n & 1) == 0) {
          const unsigned packed = f2bf(hnew) | (f2bf(pv) << 16);
          __hip_atomic_store(
              ringb + (size_t)(t & 1) * 256 + q * 64 + (n >> 1),
              ((unsigned long long)(unsigned)t << 32) | packed,
              __ATOMIC_RELAXED, __HIP_MEMORY_SCOPE_AGENT);
        }
      }
    }

    // ---- out-projection for tau = t-2 (absorbed by next step's poll) ----
    if (t >= 2 && tid < 256) {
      float s0 = 0.f, s1 = 0.f;
#pragma unroll
      for (int j = 0; j < 32; j += 2) {
        s0 = fmaf(wo[j+0], h2[hs][(j+0) >> 3][oc + 16 * ((j+0) & 7)], s0);
        s1 = fmaf(wo[j+1], h2[hs][(j+1) >> 3][oc + 16 * ((j+1) & 7)], s1);
      }
      float s = s0 + s1;
      s += __shfl_xor(s, 1);
      s += __shfl_xor(s, 2);
      s += __shfl_xor(s, 4);
      s += __shfl_xor(s, 8);
      if (oc == 0) {
        outb[(size_t)(t - 2) * OO + q * 16 + o_loc] = tanh_fast(s + bo);
      }
    }

    // ---- final hidden state h_T -> d_out tail ----
    if (t == TT + 1 && q == 0 && tid < 256) {
      const int e0 = tid * 2;
      float* hout = out + (size_t)BB * TT * OO + (size_t)b * HH + e0;
      hout[0] = h2[hs][e0 >> 7][e0 & 127];
      hout[1] = h2[hs][e0 >> 7][(e0 & 127) + 1];
    }
  }
}

extern "C" void kernel_launch(void* const* d_in, const int* in_sizes, int n_in,
                              void* d_out, int out_size, void* d_ws, size_t ws_size,
                              hipStream_t stream) {
  (void)in_sizes; (void)n_in; (void)out_size; (void)ws_size;
  const float* x    = (const float*)d_in[0];
  const float* h0   = (const float*)d_in[1];
  const float* Wih  = (const float*)d_in[2];
  const float* Whh  = (const float*)d_in[3];
  const float* bih  = (const float*)d_in[4];
  const float* bhh  = (const float*)d_in[5];
  const float* Wout = (const float*)d_in[6];
  const float* bout = (const float*)d_in[7];
  float* out = (float*)d_out;

  unsigned long long* ring = (unsigned long long*)d_ws;  // 64 x 2 x 256 x 8B

  // ring tags must be zero at the start of every (replayed) launch
  hipMemsetAsync(d_ws, 0, (size_t)BB * 2 * 256 * 8, stream);

  rnn_persist<<<dim3(256), dim3(512), 0, stream>>>(
      x, h0, Wih, Whh, bih, bhh, Wout, bout, out, ring);
}